// Round 8
// baseline (277.735 us; speedup 1.0000x reference)
//
#include <hip/hip_runtime.h>
#include <math.h>

#define BB 2
#define NN 512
#define DD 128
#define HH 8
#define DKK 16
#define TR 64            // tile rows
#define NT (NN / TR)     // 8 tiles per (b,n)

// direct global->LDS 16B DMA (dest = wave-uniform base + lane*16)
#define GL_LDS16(gp, lp)                                                     \
    __builtin_amdgcn_global_load_lds(                                        \
        (const __attribute__((address_space(1))) void*)(gp),                 \
        (__attribute__((address_space(3))) void*)(lp), 16, 0, 0)

// ---- all-VALU cross-lane sums (no LDS pipe) ----
template<int CTRL>
__device__ __forceinline__ float dpp_sum(float x) {   // x + lane-permuted x
    return x + __int_as_float(__builtin_amdgcn_mov_dpp(
        __float_as_int(x), CTRL, 0xF, 0xF, true));
}
__device__ __forceinline__ float pl16_sum(float x) {  // x + xor16(x)
#if __has_builtin(__builtin_amdgcn_permlane16_swap)
    auto p = __builtin_amdgcn_permlane16_swap(__float_as_int(x),
                                              __float_as_int(x), false, false);
    return __int_as_float(p[0]) + __int_as_float(p[1]);
#else
    return x + __shfl_xor(x, 16, 64);
#endif
}
__device__ __forceinline__ float pl32_sum(float x) {  // x + xor32(x)
#if __has_builtin(__builtin_amdgcn_permlane32_swap)
    auto p = __builtin_amdgcn_permlane32_swap(__float_as_int(x),
                                              __float_as_int(x), false, false);
    return __int_as_float(p[0]) + __int_as_float(p[1]);
#else
    return x + __shfl_xor(x, 32, 64);
#endif
}
// sum over the 16 lanes differing in bits {0,1,4,5}
__device__ __forceinline__ float red_dsl(float x) {
    x = dpp_sum<0xB1>(x);   // xor 1 (quad_perm [1,0,3,2])
    x = dpp_sum<0x4E>(x);   // xor 2 (quad_perm [2,3,0,1])
    x = pl16_sum(x);        // xor 16
    x = pl32_sum(x);        // xor 32
    return x;
}
__device__ __forceinline__ float dot4(float4 a, float4 b) {
    return a.x*b.x + a.y*b.y + a.z*b.z + a.w*b.w;
}

// ---------------- Kernel 1: QKV projection + W_egT staging ----------------
__global__ __launch_bounds__(128)
void qkv_kernel(const float* __restrict__ n_in,
                const float* __restrict__ W_qkv,
                const float* __restrict__ W_g,
                const float* __restrict__ W_e,
                float* __restrict__ Qw, float* __restrict__ Kw,
                float* __restrict__ Vw, float* __restrict__ WegT)
{
    const int bid = blockIdx.x;
    if (bid >= BB * NN) {                    // 16 trailing blocks: WegT[col][d]
        const int col = bid - BB * NN;       // 0..15
        const int t = threadIdx.x;           // 0..127
        WegT[col * DD + t] = (col < 8) ? W_e[t * HH + col]
                                       : W_g[t * HH + (col - 8)];
        return;
    }
    __shared__ float nrow[DD];
    const int bn = bid;
    const int b  = bn >> 9;
    const int nr = bn & 511;
    const int t  = threadIdx.x;
    nrow[t] = n_in[(size_t)bn * DD + t];
    __syncthreads();
    const int h = t >> 4, dk = t & 15;
    const size_t dst = ((size_t)(b * HH + h) * NN + nr) * DKK + dk;
    float accq = 0.f, acck = 0.f, accv = 0.f;
    #pragma unroll 8
    for (int d = 0; d < DD; ++d) {
        const float nv = nrow[d];
        const float* wr = W_qkv + (size_t)d * 3 * DD;
        accq += nv * wr[t];
        acck += nv * wr[t + 128];
        accv += nv * wr[t + 256];
    }
    Qw[dst] = accq;
    Kw[dst] = acck;
    Vw[dst] = accv;
}

// ---------------- Kernel 1b: QKc = clamp(Q K^T * scale), [bn][h][m] ----------------
__global__ __launch_bounds__(256)
void qk_kernel(const float* __restrict__ Qw,
               const float* __restrict__ Kw,
               float* __restrict__ QKc)
{
    __shared__ __align__(16) float4 Kl[NN * 4];   // 32KB  [m][4]
    __shared__ __align__(16) float4 Ql[32 * 4];   // 2KB   [qr][4]

    const int bid = blockIdx.x;
    const int qt  = bid & 15;
    const int h   = (bid >> 4) & 7;
    const int b   = bid >> 7;
    const int t   = threadIdx.x;

    const float4* __restrict__ kb =
        (const float4*)Kw + ((size_t)(b * HH + h) * NN) * 4;
    #pragma unroll
    for (int j = 0; j < 8; ++j) Kl[j * 256 + t] = kb[j * 256 + t];
    if (t < 128)
        Ql[t] = ((const float4*)Qw)[((size_t)(b * HH + h) * NN + qt * 32) * 4 + t];
    __syncthreads();

    const int qr = t >> 3;
    const int mq = t & 7;
    const float4 q0 = Ql[qr * 4 + 0];
    const float4 q1 = Ql[qr * 4 + 1];
    const float4 q2 = Ql[qr * 4 + 2];
    const float4 q3 = Ql[qr * 4 + 3];

    float4* __restrict__ out4 =
        (float4*)QKc + (((size_t)(b * NN + qt * 32 + qr) * HH + h) * NN) / 4;

    #pragma unroll 1
    for (int c = 0; c < 16; ++c) {
        float4 r;
        float* rp = (float*)&r;
        #pragma unroll
        for (int i = 0; i < 4; ++i) {
            const int m = mq * 64 + c * 4 + i;
            float s = dot4(q0, Kl[m*4+0]) + dot4(q1, Kl[m*4+1])
                    + dot4(q2, Kl[m*4+2]) + dot4(q3, Kl[m*4+3]);
            s *= 0.25f;
            rp[i] = fminf(5.f, fmaxf(-5.f, s));
        }
        out4[mq * 16 + c] = r;
    }
}

// ---------------- Kernel 2: fused E/G + (+QKc) + e_out ----------------
// One block per (b,n), 512 threads = 8 waves = 4 col-groups x 2 row-groups.
// Cross-lane dot reduction all-VALU (DPP + permlane swaps). LDS ops ~2/row.
__global__ __launch_bounds__(512, 4)
void eg_kernel(const float* __restrict__ e,
               const float* __restrict__ WegT,
               const float* __restrict__ O_e,
               const float* __restrict__ QKc,
               float* __restrict__ EGw,     // [B*N][H][NN] _E
               float* __restrict__ Gpart,   // [B*N][2][H]
               float* __restrict__ e_out)
{
    __shared__ __align__(16) float4 buf4[2][TR * 32];   // 2 x 32KB e-tiles
    __shared__ __align__(16) float  qkcl[2][HH * TR];   // 2 x 2KB [h][m]
    __shared__ __align__(16) float  ET2[TR][HH];        // 2KB [m][h]

    const int t    = threadIdx.x;
    const int bn   = blockIdx.x;
    const int wq   = t >> 6;                  // wave 0..7
    const int lane = t & 63;
    const int cg   = wq & 3;                  // col group: cols cg*4..+4
    const int rg   = wq >> 2;                 // row group: rows rg*32..+32
    const int dsl  = (lane & 3) | ((lane >> 2) & 12);  // bits {0,1,4,5}
    const int ml   = (lane >> 2) & 3;                  // bits {2,3}
    const int c4o  = t & 31;                  // e_out float4 column
    const int mr0  = t >> 5;                  // e_out row base 0..15

    // ---- W slices into regs: 4 cols x 8 floats (d = dsl*8 .. +8) = 32 VGPR ----
    const float4* __restrict__ WegT4 = (const float4*)WegT;
    float4 w[4][2];
    #pragma unroll
    for (int j = 0; j < 4; ++j)
        #pragma unroll
        for (int k = 0; k < 2; ++k)
            w[j][k] = WegT4[(cg * 4 + j) * 32 + dsl * 2 + k];

    // O_e column cache (32 VGPR)
    float4 oe[8];
    #pragma unroll
    for (int h = 0; h < 8; ++h)
        oe[h] = ((const float4*)O_e)[h * 32 + c4o];

    const float4* __restrict__ e4  = (const float4*)e + (size_t)bn * NN * 32;
    const float4* __restrict__ qk4 = (const float4*)QKc + (size_t)bn * HH * 128;

    // stage: 4 e-GL16/thread (pre-swizzled src: slot q holds (m, (q&31)^(m&31)))
    // + waves 0-1 stage qkc tile (1 GL16 each thread t<128)
    #define STAGE(tile, pb)                                                   \
    {                                                                         \
        _Pragma("unroll")                                                     \
        for (int j = 0; j < 4; ++j) {                                         \
            const int q  = j * 512 + t;                                       \
            const int m_ = q >> 5, x_ = q & 31;                               \
            GL_LDS16(e4 + (size_t)(tile) * 2048 + m_ * 32 + (x_ ^ (m_ & 31)), \
                     &buf4[pb][j * 512 + (t & ~63)]);                         \
        }                                                                     \
        if (t < 128) {                                                        \
            GL_LDS16(qk4 + (t >> 4) * 128 + (tile) * 16 + (t & 15),           \
                     &qkcl[pb][(t & ~63) * 4]);                               \
        }                                                                     \
    }

    #define PHASE_A(tt, pb)                                                   \
    {                                                                         \
        const float4* __restrict__ bp = buf4[pb];                             \
        _Pragma("unroll")                                                     \
        for (int batch = 0; batch < 8; ++batch) {                             \
            const int m31 = batch * 4 + ml;                                   \
            const int m   = rg * 32 + m31;                                    \
            const int s0  = (dsl * 2) ^ m31;                                  \
            const float4 ev0 = bp[m * 32 + s0];                               \
            const float4 ev1 = bp[m * 32 + (s0 ^ 1)];                         \
            float a0 = dot4(ev0, w[0][0]) + dot4(ev1, w[0][1]);               \
            float a1 = dot4(ev0, w[1][0]) + dot4(ev1, w[1][1]);               \
            float a2 = dot4(ev0, w[2][0]) + dot4(ev1, w[2][1]);               \
            float a3 = dot4(ev0, w[3][0]) + dot4(ev1, w[3][1]);               \
            a0 = red_dsl(a0); a1 = red_dsl(a1);                               \
            a2 = red_dsl(a2); a3 = red_dsl(a3);                               \
            if (cg < 2) {       /* E cols: write _E */                        \
                float v; int c;                                               \
                if (dsl == 0) { c = cg*4+0; v = a0 + qkcl[pb][c*TR + m];      \
                    ET2[m][c] = v; EGw[((size_t)bn*HH+c)*NN + (tt)*TR+m] = v; }\
                if (dsl == 1) { c = cg*4+1; v = a1 + qkcl[pb][c*TR + m];      \
                    ET2[m][c] = v; EGw[((size_t)bn*HH+c)*NN + (tt)*TR+m] = v; }\
                if (dsl == 2) { c = cg*4+2; v = a2 + qkcl[pb][c*TR + m];      \
                    ET2[m][c] = v; EGw[((size_t)bn*HH+c)*NN + (tt)*TR+m] = v; }\
                if (dsl == 3) { c = cg*4+3; v = a3 + qkcl[pb][c*TR + m];      \
                    ET2[m][c] = v; EGw[((size_t)bn*HH+c)*NN + (tt)*TR+m] = v; }\
            } else {            /* G cols: accumulate sigmoid sums */         \
                ga0 += 1.f / (1.f + __expf(-a0));                             \
                ga1 += 1.f / (1.f + __expf(-a1));                             \
                ga2 += 1.f / (1.f + __expf(-a2));                             \
                ga3 += 1.f / (1.f + __expf(-a3));                             \
            }                                                                 \
        }                                                                     \
    }

    #define PHASE_C(tt)                                                       \
    {                                                                         \
        float4* __restrict__ out4 =                                           \
            (float4*)e_out + ((size_t)bn * NN + (tt) * TR) * 32;              \
        _Pragma("unroll")                                                     \
        for (int it = 0; it < 4; ++it) {                                      \
            const int m = mr0 + it * 16;                                      \
            const float4 elo = *(const float4*)&ET2[m][0];                    \
            const float4 ehi = *(const float4*)&ET2[m][4];                    \
            float4 rr;                                                        \
            rr.x = elo.x*oe[0].x + elo.y*oe[1].x + elo.z*oe[2].x + elo.w*oe[3].x \
                 + ehi.x*oe[4].x + ehi.y*oe[5].x + ehi.z*oe[6].x + ehi.w*oe[7].x; \
            rr.y = elo.x*oe[0].y + elo.y*oe[1].y + elo.z*oe[2].y + elo.w*oe[3].y \
                 + ehi.x*oe[4].y + ehi.y*oe[5].y + ehi.z*oe[6].y + ehi.w*oe[7].y; \
            rr.z = elo.x*oe[0].z + elo.y*oe[1].z + elo.z*oe[2].z + elo.w*oe[3].z \
                 + ehi.x*oe[4].z + ehi.y*oe[5].z + ehi.z*oe[6].z + ehi.w*oe[7].z; \
            rr.w = elo.x*oe[0].w + elo.y*oe[1].w + elo.z*oe[2].w + elo.w*oe[3].w \
                 + ehi.x*oe[4].w + ehi.y*oe[5].w + ehi.z*oe[6].w + ehi.w*oe[7].w; \
            out4[m * 32 + c4o] = rr;                                          \
        }                                                                     \
    }

    float ga0 = 0.f, ga1 = 0.f, ga2 = 0.f, ga3 = 0.f;

    STAGE(0, 0);
    asm volatile("s_waitcnt vmcnt(0)" ::: "memory");
    __builtin_amdgcn_s_barrier();

    int p = 0;
    #pragma unroll 1
    for (int tt = 0; tt < NT; ++tt) {
        if (tt + 1 < NT) {
            STAGE(tt + 1, p ^ 1);
            // per-wave exact gate: waves 0-1 issue 5 loads/stage, others 4
            if (wq < 2) { asm volatile("s_waitcnt vmcnt(5)" ::: "memory"); }
            else        { asm volatile("s_waitcnt vmcnt(4)" ::: "memory"); }
        } else {
            asm volatile("s_waitcnt vmcnt(0)" ::: "memory");
        }
        __builtin_amdgcn_s_barrier();   // buf[p], qkcl[p] complete everywhere

        PHASE_A(tt, p);
        asm volatile("s_waitcnt lgkmcnt(0)" ::: "memory");
        __builtin_amdgcn_s_barrier();   // ET2 final

        PHASE_C(tt);
        p ^= 1;
    }

    // ---- final G reduction: sum over ml lanes (bits 2,3), write per rg ----
    if (cg >= 2) {
        ga0 += __shfl_xor(ga0, 4, 64);  ga0 += __shfl_xor(ga0, 8, 64);
        ga1 += __shfl_xor(ga1, 4, 64);  ga1 += __shfl_xor(ga1, 8, 64);
        ga2 += __shfl_xor(ga2, 4, 64);  ga2 += __shfl_xor(ga2, 8, 64);
        ga3 += __shfl_xor(ga3, 4, 64);  ga3 += __shfl_xor(ga3, 8, 64);
        if (lane == 0) {
            float* gp = Gpart + ((size_t)bn * 2 + rg) * HH + (cg - 2) * 4;
            gp[0] = ga0; gp[1] = ga1; gp[2] = ga2; gp[3] = ga3;
        }
    }
    #undef STAGE
    #undef PHASE_A
    #undef PHASE_C
}

// ---------------- Kernel 3: softmax + AV + n_out ----------------
__global__ __launch_bounds__(256)
void attn_kernel(const float* __restrict__ EGw,
                 const float* __restrict__ Gpart,
                 const float* __restrict__ Vw,
                 const float* __restrict__ O_n,
                 float* __restrict__ n_out)
{
    __shared__ __align__(16) float ET[HH * NN];   // 16KB
    __shared__ __align__(16) float vout[DD];
    __shared__ float dc[HH];

    const int t    = threadIdx.x;
    const int bn   = blockIdx.x;
    const int b    = bn >> 9;
    const int wq   = t >> 6;
    const int lane = t & 63;

    const float4* __restrict__ eg4 = (const float4*)(EGw + (size_t)bn * HH * NN);
    float4* et4 = (float4*)ET;
    #pragma unroll
    for (int i = t; i < HH * NN / 4; i += 256) et4[i] = eg4[i];
    if (t < HH)
        dc[t] = log1pf(Gpart[(size_t)bn * 2 * HH + t] +
                       Gpart[(size_t)bn * 2 * HH + HH + t]);
    __syncthreads();

    #pragma unroll 1
    for (int hw = 0; hw < 2; ++hw) {
        const int h = wq * 2 + hw;
        float vals[8];
        float rmax = -1e30f;
        #pragma unroll
        for (int k = 0; k < 8; ++k) {
            vals[k] = ET[h * NN + k * 64 + lane];
            rmax = fmaxf(rmax, vals[k]);
        }
        #pragma unroll
        for (int off = 32; off >= 1; off >>= 1)
            rmax = fmaxf(rmax, __shfl_xor(rmax, off, 64));
        float sum = 0.f;
        #pragma unroll
        for (int k = 0; k < 8; ++k) sum += __expf(vals[k] - rmax);
        #pragma unroll
        for (int off = 32; off >= 1; off >>= 1)
            sum += __shfl_xor(sum, off, 64);
        const float factor = dc[h] / sum;

        const int ddx = lane & 15, mg = lane >> 4;
        const float* __restrict__ vb = Vw + ((size_t)(b * HH + h) * NN) * DKK;
        float av = 0.f;
        #pragma unroll 4
        for (int m = mg; m < NN; m += 4) {
            const float p = __expf(ET[h * NN + m] - rmax);
            av += p * vb[m * DKK + ddx];
        }
        av += __shfl_xor(av, 16, 64);
        av += __shfl_xor(av, 32, 64);
        if (mg == 0) vout[h * DKK + ddx] = av * factor;
    }
    __syncthreads();

    if (t < DD) {
        float a3 = 0.f;
        #pragma unroll 4
        for (int d = 0; d < DD; ++d) a3 += vout[d] * O_n[d * DD + t];
        n_out[(size_t)bn * DD + t] = a3;
    }
}

extern "C" void kernel_launch(void* const* d_in, const int* in_sizes, int n_in,
                              void* d_out, int out_size, void* d_ws, size_t ws_size,
                              hipStream_t stream)
{
    const float* n_ptr = (const float*)d_in[0];
    const float* e     = (const float*)d_in[1];
    const float* W_qkv = (const float*)d_in[2];
    const float* O_n   = (const float*)d_in[3];
    const float* W_g   = (const float*)d_in[4];
    const float* W_e   = (const float*)d_in[5];
    const float* O_e   = (const float*)d_in[6];

    float* n_out = (float*)d_out;
    float* e_out = n_out + (size_t)BB * NN * DD;

    float* Qw    = (float*)d_ws;                          // 3 x 0.5MB
    float* Kw    = Qw + (size_t)BB * HH * NN * DKK;
    float* Vw    = Kw + (size_t)BB * HH * NN * DKK;
    float* EGw   = Vw + (size_t)BB * HH * NN * DKK;       // 16.8MB
    float* QKc   = EGw + (size_t)BB * HH * NN * NN;       // 16.8MB
    float* Gpart = QKc + (size_t)BB * HH * NN * NN;       // 64KB
    float* WegT  = Gpart + (size_t)BB * NN * 2 * HH;      // 8KB

    qkv_kernel<<<BB * NN + 16, 128, 0, stream>>>(n_ptr, W_qkv, W_g, W_e,
                                                 Qw, Kw, Vw, WegT);
    qk_kernel<<<BB * HH * 16, 256, 0, stream>>>(Qw, Kw, QKc);
    eg_kernel<<<BB * NN, 512, 0, stream>>>(e, WegT, O_e, QKc,
                                           EGw, Gpart, e_out);
    attn_kernel<<<BB * NN, 256, 0, stream>>>(EGw, Gpart, Vw, O_n, n_out);
}

// Round 9
// 189.738 us; speedup vs baseline: 1.4638x; 1.4638x over previous
//
#include <hip/hip_runtime.h>
#include <math.h>

#define BB 2
#define NN 512
#define DD 128
#define HH 8
#define DKK 16
#define TR 128           // tile rows
#define NT (NN / TR)     // 4 tiles per (b,n)

typedef __attribute__((ext_vector_type(8))) short short8;
typedef __attribute__((ext_vector_type(4))) float f32x4;

__device__ __forceinline__ float dot4(float4 a, float4 b) {
    return a.x*b.x + a.y*b.y + a.z*b.z + a.w*b.w;
}
// RNE f32 -> bf16 pack (a in low, b in high)
__device__ __forceinline__ unsigned pk_bf16(float a, float b) {
    unsigned ua = __float_as_uint(a), ub = __float_as_uint(b);
    ua = (ua + 0x7FFFu + ((ua >> 16) & 1u)) >> 16;
    ub = (ub + 0x7FFFu + ((ub >> 16) & 1u)) >> 16;
    return ua | (ub << 16);
}

// ---------------- Kernel 1: QKV projection + W_egT staging ----------------
__global__ __launch_bounds__(128)
void qkv_kernel(const float* __restrict__ n_in,
                const float* __restrict__ W_qkv,
                const float* __restrict__ W_g,
                const float* __restrict__ W_e,
                float* __restrict__ Qw, float* __restrict__ Kw,
                float* __restrict__ Vw, float* __restrict__ WegT)
{
    const int bid = blockIdx.x;
    if (bid >= BB * NN) {                    // 16 trailing blocks: WegT[col][d]
        const int col = bid - BB * NN;       // 0..15
        const int t = threadIdx.x;           // 0..127
        WegT[col * DD + t] = (col < 8) ? W_e[t * HH + col]
                                       : W_g[t * HH + (col - 8)];
        return;
    }
    __shared__ float nrow[DD];
    const int bn = bid;
    const int b  = bn >> 9;
    const int nr = bn & 511;
    const int t  = threadIdx.x;
    nrow[t] = n_in[(size_t)bn * DD + t];
    __syncthreads();
    const int h = t >> 4, dk = t & 15;
    const size_t dst = ((size_t)(b * HH + h) * NN + nr) * DKK + dk;
    float accq = 0.f, acck = 0.f, accv = 0.f;
    #pragma unroll 8
    for (int d = 0; d < DD; ++d) {
        const float nv = nrow[d];
        const float* wr = W_qkv + (size_t)d * 3 * DD;
        accq += nv * wr[t];
        acck += nv * wr[t + 128];
        accv += nv * wr[t + 256];
    }
    Qw[dst] = accq;
    Kw[dst] = acck;
    Vw[dst] = accv;
}

// ---------------- Kernel 1b: QKc = clamp(Q K^T * scale), [bn][h][m] ----------------
__global__ __launch_bounds__(256)
void qk_kernel(const float* __restrict__ Qw,
               const float* __restrict__ Kw,
               float* __restrict__ QKc)
{
    __shared__ __align__(16) float4 Kl[NN * 4];   // 32KB  [m][4]
    __shared__ __align__(16) float4 Ql[32 * 4];   // 2KB   [qr][4]

    const int bid = blockIdx.x;
    const int qt  = bid & 15;
    const int h   = (bid >> 4) & 7;
    const int b   = bid >> 7;
    const int t   = threadIdx.x;

    const float4* __restrict__ kb =
        (const float4*)Kw + ((size_t)(b * HH + h) * NN) * 4;
    #pragma unroll
    for (int j = 0; j < 8; ++j) Kl[j * 256 + t] = kb[j * 256 + t];
    if (t < 128)
        Ql[t] = ((const float4*)Qw)[((size_t)(b * HH + h) * NN + qt * 32) * 4 + t];
    __syncthreads();

    const int qr = t >> 3;
    const int mq = t & 7;
    const float4 q0 = Ql[qr * 4 + 0];
    const float4 q1 = Ql[qr * 4 + 1];
    const float4 q2 = Ql[qr * 4 + 2];
    const float4 q3 = Ql[qr * 4 + 3];

    float4* __restrict__ out4 =
        (float4*)QKc + (((size_t)(b * NN + qt * 32 + qr) * HH + h) * NN) / 4;

    #pragma unroll 1
    for (int c = 0; c < 16; ++c) {
        float4 r;
        float* rp = (float*)&r;
        #pragma unroll
        for (int i = 0; i < 4; ++i) {
            const int m = mq * 64 + c * 4 + i;
            float s = dot4(q0, Kl[m*4+0]) + dot4(q1, Kl[m*4+1])
                    + dot4(q2, Kl[m*4+2]) + dot4(q3, Kl[m*4+3]);
            s *= 0.25f;
            rp[i] = fminf(5.f, fmaxf(-5.f, s));
        }
        out4[mq * 16 + c] = r;
    }
}

// ---------------- Kernel 2: fused E/G (MFMA bf16) + QKc + e_out ----------------
// One block per (b,n), 512 threads = 8 waves. e-tile (128 rows) staged as
// bf16 in LDS (XOR chunk^row swizzle); E[.,16cols] = e@Weg via one
// mfma_f32_16x16x32_bf16 m-block per wave, K in 4 steps. e read ONCE from LDS.
__global__ __launch_bounds__(512, 2)
void eg_kernel(const float* __restrict__ e,
               const float* __restrict__ WegT,
               const float* __restrict__ O_e,
               const float* __restrict__ QKc,
               float* __restrict__ EGw,     // [B*N][H][NN] _E
               float* __restrict__ Gfull,   // [B*N][H]
               float* __restrict__ e_out)
{
    __shared__ __align__(16) uint4 ebuf4[2][TR * 16];  // 2 x 32KB bf16 tiles
    __shared__ __align__(16) float ET2[TR * HH];       // 4KB [m][c<8]
    __shared__ float Gred[64];                         // [wave][gcol]

    const int t    = threadIdx.x;
    const int bn   = blockIdx.x;
    const int wq   = t >> 6;
    const int lane = t & 63;
    const int c    = lane & 15;      // MFMA C/D col  (= W col / head)
    const int mq   = lane >> 4;      // C/D row group (rows mq*4+j)
    const int kgrp = lane >> 4;      // A/B k-group
    const int c4o  = t & 31;         // e_out float4 column
    const int mr0  = t >> 5;         // e_out row base 0..15

    const float4* __restrict__ e4    = (const float4*)e + (size_t)bn * NN * 32;
    const float4* __restrict__ WegT4 = (const float4*)WegT;

    // ---- B fragments: W[col=c][k] -> bf16, 4 k-steps (16 VGPR) ----
    short8 wB[4];
    #pragma unroll
    for (int kb = 0; kb < 4; ++kb) {
        const float4 wa = WegT4[c * 32 + kb * 8 + kgrp * 2];
        const float4 wb = WegT4[c * 32 + kb * 8 + kgrp * 2 + 1];
        uint4 u;
        u.x = pk_bf16(wa.x, wa.y); u.y = pk_bf16(wa.z, wa.w);
        u.z = pk_bf16(wb.x, wb.y); u.w = pk_bf16(wb.z, wb.w);
        wB[kb] = *(short8*)&u;
    }
    // ---- O_e column cache ----
    float4 oe[8];
    #pragma unroll
    for (int h = 0; h < 8; ++h)
        oe[h] = ((const float4*)O_e)[h * 32 + c4o];

    // stage-load regs: 8 float4 (32 VGPR)
    float4 pa0, pa1, pa2, pa3, pb0, pb1, pb2, pb3;

    #define STAGE_LOAD(tile)                                                  \
    {                                                                         \
        const float4* __restrict__ sp = e4 + (size_t)(tile) * 4096 + 2 * t;   \
        pa0 = sp[0];    pb0 = sp[1];                                          \
        pa1 = sp[1024]; pb1 = sp[1025];                                       \
        pa2 = sp[2048]; pb2 = sp[2049];                                       \
        pa3 = sp[3072]; pb3 = sp[3073];                                       \
    }
    #define STAGE_WRITE(dst, P, A, B)                                         \
    {                                                                         \
        const int ms = (P) * 32 + (t >> 4), ck = t & 15;                      \
        uint4 u;                                                              \
        u.x = pk_bf16(A.x, A.y); u.y = pk_bf16(A.z, A.w);                     \
        u.z = pk_bf16(B.x, B.y); u.w = pk_bf16(B.z, B.w);                     \
        ebuf4[dst][ms * 16 + (ck ^ (ms & 15))] = u;                           \
    }
    #define STAGE_WRITE_ALL(dst)                                              \
    {                                                                         \
        STAGE_WRITE(dst, 0, pa0, pb0); STAGE_WRITE(dst, 1, pa1, pb1);         \
        STAGE_WRITE(dst, 2, pa2, pb2); STAGE_WRITE(dst, 3, pa3, pb3);         \
    }

    float ga0 = 0.f, ga1 = 0.f, ga2 = 0.f, ga3 = 0.f;

    // ---- prologue: tile 0 ----
    STAGE_LOAD(0);
    STAGE_WRITE_ALL(0);
    asm volatile("s_waitcnt lgkmcnt(0)" ::: "memory");
    __builtin_amdgcn_s_barrier();

    #pragma unroll
    for (int tt = 0; tt < NT; ++tt) {
        const int pb = tt & 1;

        // qkc for this tile (E-cols only)
        float4 qkv4 = {0.f, 0.f, 0.f, 0.f};
        if (c < 8)
            qkv4 = *(const float4*)(QKc + ((size_t)bn * HH + c) * NN
                                    + tt * TR + wq * 16 + mq * 4);
        // prefetch next tile into regs (stays in flight across barriers)
        if (tt + 1 < NT) STAGE_LOAD(tt + 1);

        // ---- MFMA: E/G for this wave's 16 rows x 16 cols ----
        const int mrow = wq * 16 + (lane & 15);
        f32x4 acc = {0.f, 0.f, 0.f, 0.f};
        #pragma unroll
        for (int kb = 0; kb < 4; ++kb) {
            const int ck = kb * 4 + kgrp;
            uint4 av = ebuf4[pb][mrow * 16 + (ck ^ (mrow & 15))];
            acc = __builtin_amdgcn_mfma_f32_16x16x32_bf16(
                      *(short8*)&av, wB[kb], acc, 0, 0, 0);
        }

        // ---- epilogue: _E / G split ----
        const int mloc = wq * 16 + mq * 4;
        if (c < 8) {
            float4 v;
            v.x = acc[0] + qkv4.x;  v.y = acc[1] + qkv4.y;
            v.z = acc[2] + qkv4.z;  v.w = acc[3] + qkv4.w;
            *(float4*)(EGw + ((size_t)bn * HH + c) * NN + tt * TR + mloc) = v;
            ET2[(mloc + 0) * HH + c] = v.x;
            ET2[(mloc + 1) * HH + c] = v.y;
            ET2[(mloc + 2) * HH + c] = v.z;
            ET2[(mloc + 3) * HH + c] = v.w;
        } else {
            ga0 += 1.f / (1.f + __expf(-acc[0]));
            ga1 += 1.f / (1.f + __expf(-acc[1]));
            ga2 += 1.f / (1.f + __expf(-acc[2]));
            ga3 += 1.f / (1.f + __expf(-acc[3]));
        }
        asm volatile("s_waitcnt lgkmcnt(0)" ::: "memory");
        __builtin_amdgcn_s_barrier();   // ET2 final; ebuf[pb] reads done

        // ---- PHASE_C: e_out tile (c<8 cols of ET2 @ O_e) ----
        {
            float4* __restrict__ out4 =
                (float4*)e_out + ((size_t)bn * NN + tt * TR) * 32;
            #pragma unroll
            for (int it = 0; it < 8; ++it) {
                const int m = mr0 + it * 16;
                const float4 elo = *(const float4*)&ET2[m * HH + 0];
                const float4 ehi = *(const float4*)&ET2[m * HH + 4];
                float4 rr;
                rr.x = elo.x*oe[0].x + elo.y*oe[1].x + elo.z*oe[2].x + elo.w*oe[3].x
                     + ehi.x*oe[4].x + ehi.y*oe[5].x + ehi.z*oe[6].x + ehi.w*oe[7].x;
                rr.y = elo.x*oe[0].y + elo.y*oe[1].y + elo.z*oe[2].y + elo.w*oe[3].y
                     + ehi.x*oe[4].y + ehi.y*oe[5].y + ehi.z*oe[6].y + ehi.w*oe[7].y;
                rr.z = elo.x*oe[0].z + elo.y*oe[1].z + elo.z*oe[2].z + elo.w*oe[3].z
                     + ehi.x*oe[4].z + ehi.y*oe[5].z + ehi.z*oe[6].z + ehi.w*oe[7].z;
                rr.w = elo.x*oe[0].w + elo.y*oe[1].w + elo.z*oe[2].w + elo.w*oe[3].w
                     + ehi.x*oe[4].w + ehi.y*oe[5].w + ehi.z*oe[6].w + ehi.w*oe[7].w;
                out4[m * 32 + c4o] = rr;
            }
        }

        // ---- refill other buffer from prefetched regs ----
        if (tt + 1 < NT) {
            STAGE_WRITE_ALL(pb ^ 1);   // compiler waits the prefetch loads
            asm volatile("s_waitcnt lgkmcnt(0)" ::: "memory");
            __builtin_amdgcn_s_barrier();
        }
    }

    // ---- G reduction: per-wave col sums -> Gred -> Gfull ----
    if (c >= 8) {
        float s = ga0 + ga1 + ga2 + ga3;
        s += __shfl_xor(s, 16, 64);
        s += __shfl_xor(s, 32, 64);
        if (lane < 16) Gred[wq * 8 + (c - 8)] = s;
    }
    __syncthreads();
    if (t < 8) {
        float s = 0.f;
        #pragma unroll
        for (int w = 0; w < 8; ++w) s += Gred[w * 8 + t];
        Gfull[(size_t)bn * HH + t] = s;
    }
    #undef STAGE_LOAD
    #undef STAGE_WRITE
    #undef STAGE_WRITE_ALL
}

// ---------------- Kernel 3: softmax + AV + n_out ----------------
__global__ __launch_bounds__(256)
void attn_kernel(const float* __restrict__ EGw,
                 const float* __restrict__ Gfull,
                 const float* __restrict__ Vw,
                 const float* __restrict__ O_n,
                 float* __restrict__ n_out)
{
    __shared__ __align__(16) float ET[HH * NN];   // 16KB
    __shared__ __align__(16) float vout[DD];
    __shared__ float dc[HH];

    const int t    = threadIdx.x;
    const int bn   = blockIdx.x;
    const int b    = bn >> 9;
    const int wq   = t >> 6;
    const int lane = t & 63;

    const float4* __restrict__ eg4 = (const float4*)(EGw + (size_t)bn * HH * NN);
    float4* et4 = (float4*)ET;
    #pragma unroll
    for (int i = t; i < HH * NN / 4; i += 256) et4[i] = eg4[i];
    if (t < HH) dc[t] = log1pf(Gfull[(size_t)bn * HH + t]);
    __syncthreads();

    #pragma unroll 1
    for (int hw = 0; hw < 2; ++hw) {
        const int h = wq * 2 + hw;
        float vals[8];
        float rmax = -1e30f;
        #pragma unroll
        for (int k = 0; k < 8; ++k) {
            vals[k] = ET[h * NN + k * 64 + lane];
            rmax = fmaxf(rmax, vals[k]);
        }
        #pragma unroll
        for (int off = 32; off >= 1; off >>= 1)
            rmax = fmaxf(rmax, __shfl_xor(rmax, off, 64));
        float sum = 0.f;
        #pragma unroll
        for (int k = 0; k < 8; ++k) sum += __expf(vals[k] - rmax);
        #pragma unroll
        for (int off = 32; off >= 1; off >>= 1)
            sum += __shfl_xor(sum, off, 64);
        const float factor = dc[h] / sum;

        const int ddx = lane & 15, mg = lane >> 4;
        const float* __restrict__ vb = Vw + ((size_t)(b * HH + h) * NN) * DKK;
        float av = 0.f;
        #pragma unroll 4
        for (int m = mg; m < NN; m += 4) {
            const float p = __expf(ET[h * NN + m] - rmax);
            av += p * vb[m * DKK + ddx];
        }
        av += __shfl_xor(av, 16, 64);
        av += __shfl_xor(av, 32, 64);
        if (mg == 0) vout[h * DKK + ddx] = av * factor;
    }
    __syncthreads();

    if (t < DD) {
        float a3 = 0.f;
        #pragma unroll 4
        for (int d = 0; d < DD; ++d) a3 += vout[d] * O_n[d * DD + t];
        n_out[(size_t)bn * DD + t] = a3;
    }
}

extern "C" void kernel_launch(void* const* d_in, const int* in_sizes, int n_in,
                              void* d_out, int out_size, void* d_ws, size_t ws_size,
                              hipStream_t stream)
{
    const float* n_ptr = (const float*)d_in[0];
    const float* e     = (const float*)d_in[1];
    const float* W_qkv = (const float*)d_in[2];
    const float* O_n   = (const float*)d_in[3];
    const float* W_g   = (const float*)d_in[4];
    const float* W_e   = (const float*)d_in[5];
    const float* O_e   = (const float*)d_in[6];

    float* n_out = (float*)d_out;
    float* e_out = n_out + (size_t)BB * NN * DD;

    float* Qw    = (float*)d_ws;                          // 3 x 0.5MB
    float* Kw    = Qw + (size_t)BB * HH * NN * DKK;
    float* Vw    = Kw + (size_t)BB * HH * NN * DKK;
    float* EGw   = Vw + (size_t)BB * HH * NN * DKK;       // 16.8MB
    float* QKc   = EGw + (size_t)BB * HH * NN * NN;       // 16.8MB
    float* Gfull = QKc + (size_t)BB * HH * NN * NN;       // 32KB
    float* WegT  = Gfull + (size_t)BB * NN * HH;          // 8KB

    qkv_kernel<<<BB * NN + 16, 128, 0, stream>>>(n_ptr, W_qkv, W_g, W_e,
                                                 Qw, Kw, Vw, WegT);
    qk_kernel<<<BB * HH * 16, 256, 0, stream>>>(Qw, Kw, QKc);
    eg_kernel<<<BB * NN, 512, 0, stream>>>(e, WegT, O_e, QKc,
                                           EGw, Gfull, e_out);
    attn_kernel<<<BB * NN, 256, 0, stream>>>(EGw, Gfull, Vw, O_n, n_out);
}

// Round 10
// 172.960 us; speedup vs baseline: 1.6058x; 1.0970x over previous
//
#include <hip/hip_runtime.h>
#include <math.h>

#define BB 2
#define NN 512
#define DD 128
#define HH 8
#define DKK 16
#define TR 128           // tile rows
#define NT (NN / TR)     // 4 tiles per (b,n)

typedef __attribute__((ext_vector_type(8))) short short8;
typedef __attribute__((ext_vector_type(4))) float f32x4;

__device__ __forceinline__ float dot4(float4 a, float4 b) {
    return a.x*b.x + a.y*b.y + a.z*b.z + a.w*b.w;
}
// RNE f32 -> bf16 pack (a in low, b in high)
__device__ __forceinline__ unsigned pk_bf16(float a, float b) {
    unsigned ua = __float_as_uint(a), ub = __float_as_uint(b);
    ua = (ua + 0x7FFFu + ((ua >> 16) & 1u)) >> 16;
    ub = (ub + 0x7FFFu + ((ub >> 16) & 1u)) >> 16;
    return ua | (ub << 16);
}

// ---------------- Kernel 1: QKV projection + W_egT staging ----------------
__global__ __launch_bounds__(128)
void qkv_kernel(const float* __restrict__ n_in,
                const float* __restrict__ W_qkv,
                const float* __restrict__ W_g,
                const float* __restrict__ W_e,
                float* __restrict__ Qw, float* __restrict__ Kw,
                float* __restrict__ Vw, float* __restrict__ WegT)
{
    const int bid = blockIdx.x;
    if (bid >= BB * NN) {                    // 16 trailing blocks: WegT[col][d]
        const int col = bid - BB * NN;       // 0..15
        const int t = threadIdx.x;           // 0..127
        WegT[col * DD + t] = (col < 8) ? W_e[t * HH + col]
                                       : W_g[t * HH + (col - 8)];
        return;
    }
    __shared__ float nrow[DD];
    const int bn = bid;
    const int b  = bn >> 9;
    const int nr = bn & 511;
    const int t  = threadIdx.x;
    nrow[t] = n_in[(size_t)bn * DD + t];
    __syncthreads();
    const int h = t >> 4, dk = t & 15;
    const size_t dst = ((size_t)(b * HH + h) * NN + nr) * DKK + dk;
    float accq = 0.f, acck = 0.f, accv = 0.f;
    #pragma unroll 8
    for (int d = 0; d < DD; ++d) {
        const float nv = nrow[d];
        const float* wr = W_qkv + (size_t)d * 3 * DD;
        accq += nv * wr[t];
        acck += nv * wr[t + 128];
        accv += nv * wr[t + 256];
    }
    Qw[dst] = accq;
    Kw[dst] = acck;
    Vw[dst] = accv;
}

// ---------------- Kernel 1b: QKc = clamp(Q K^T * scale), [bn][h][m] ----------------
__global__ __launch_bounds__(256)
void qk_kernel(const float* __restrict__ Qw,
               const float* __restrict__ Kw,
               float* __restrict__ QKc)
{
    __shared__ __align__(16) float4 Kl[NN * 4];   // 32KB  [m][4]
    __shared__ __align__(16) float4 Ql[32 * 4];   // 2KB   [qr][4]

    const int bid = blockIdx.x;
    const int qt  = bid & 15;
    const int h   = (bid >> 4) & 7;
    const int b   = bid >> 7;
    const int t   = threadIdx.x;

    const float4* __restrict__ kb =
        (const float4*)Kw + ((size_t)(b * HH + h) * NN) * 4;
    #pragma unroll
    for (int j = 0; j < 8; ++j) Kl[j * 256 + t] = kb[j * 256 + t];
    if (t < 128)
        Ql[t] = ((const float4*)Qw)[((size_t)(b * HH + h) * NN + qt * 32) * 4 + t];
    __syncthreads();

    const int qr = t >> 3;
    const int mq = t & 7;
    const float4 q0 = Ql[qr * 4 + 0];
    const float4 q1 = Ql[qr * 4 + 1];
    const float4 q2 = Ql[qr * 4 + 2];
    const float4 q3 = Ql[qr * 4 + 3];

    float4* __restrict__ out4 =
        (float4*)QKc + (((size_t)(b * NN + qt * 32 + qr) * HH + h) * NN) / 4;

    #pragma unroll 1
    for (int c = 0; c < 16; ++c) {
        float4 r;
        float* rp = (float*)&r;
        #pragma unroll
        for (int i = 0; i < 4; ++i) {
            const int m = mq * 64 + c * 4 + i;
            float s = dot4(q0, Kl[m*4+0]) + dot4(q1, Kl[m*4+1])
                    + dot4(q2, Kl[m*4+2]) + dot4(q3, Kl[m*4+3]);
            s *= 0.25f;
            rp[i] = fminf(5.f, fmaxf(-5.f, s));
        }
        out4[mq * 16 + c] = r;
    }
}

// ---------------- Kernel 2: fully fused E/G (MFMA) + e_out + softmax/AV + n_out ----
// One block per (b,n), 512 threads = 8 waves. _E kept in persistent LDS
// ET[h][512]; no EGw round-trip, no separate attention kernel.
__global__ __attribute__((amdgpu_flat_work_group_size(512, 512),
                          amdgpu_waves_per_eu(2, 4)))
void eg_kernel(const float* __restrict__ e,
               const float* __restrict__ WegT,
               const float* __restrict__ O_e,
               const float* __restrict__ QKc,
               const float* __restrict__ Vw,
               const float* __restrict__ O_n,
               float* __restrict__ n_out,
               float* __restrict__ e_out)
{
    __shared__ __align__(16) uint4 ebuf4[TR * 16];   // 32KB bf16 tile (single)
    __shared__ __align__(16) float ET[HH * NN];      // 16KB persistent _E [h][m]
    __shared__ float Gred[64];
    __shared__ float dc[HH];
    __shared__ __align__(16) float vout[DD];

    const int t    = threadIdx.x;
    const int bn   = blockIdx.x;
    const int b    = bn >> 9;
    const int wq   = t >> 6;
    const int lane = t & 63;
    const int c    = lane & 15;      // MFMA C/D col (= W col / head)
    const int mq   = lane >> 4;      // C/D row group; also A/B k-group
    const int c4o  = t & 31;         // e_out float4 column
    const int mr0  = t >> 5;         // e_out row base 0..15

    const float4* __restrict__ e4    = (const float4*)e + (size_t)bn * NN * 32;
    const float4* __restrict__ WegT4 = (const float4*)WegT;

    // ---- B fragments: W[col=c][k] -> bf16, 4 k-steps (16 VGPR) ----
    short8 wB[4];
    #pragma unroll
    for (int kb = 0; kb < 4; ++kb) {
        const float4 wa = WegT4[c * 32 + kb * 8 + mq * 2];
        const float4 wb = WegT4[c * 32 + kb * 8 + mq * 2 + 1];
        uint4 u;
        u.x = pk_bf16(wa.x, wa.y); u.y = pk_bf16(wa.z, wa.w);
        u.z = pk_bf16(wb.x, wb.y); u.w = pk_bf16(wb.z, wb.w);
        wB[kb] = *(short8*)&u;
    }

    // stage-load regs: 8 float4 (32 VGPR)
    float4 pa0, pa1, pa2, pa3, pb0, pb1, pb2, pb3;

    #define STAGE_LOAD(tile)                                                  \
    {                                                                         \
        const float4* __restrict__ sp = e4 + (size_t)(tile) * 4096 + 2 * t;   \
        pa0 = sp[0];    pb0 = sp[1];                                          \
        pa1 = sp[1024]; pb1 = sp[1025];                                       \
        pa2 = sp[2048]; pb2 = sp[2049];                                       \
        pa3 = sp[3072]; pb3 = sp[3073];                                       \
    }
    #define STAGE_WRITE(P, A, B)                                              \
    {                                                                         \
        const int ms = (P) * 32 + (t >> 4), ck = t & 15;                      \
        uint4 u;                                                              \
        u.x = pk_bf16(A.x, A.y); u.y = pk_bf16(A.z, A.w);                     \
        u.z = pk_bf16(B.x, B.y); u.w = pk_bf16(B.z, B.w);                     \
        ebuf4[ms * 16 + (ck ^ (ms & 15))] = u;                                \
    }
    #define STAGE_WRITE_ALL()                                                 \
    {                                                                         \
        STAGE_WRITE(0, pa0, pb0); STAGE_WRITE(1, pa1, pb1);                   \
        STAGE_WRITE(2, pa2, pb2); STAGE_WRITE(3, pa3, pb3);                   \
    }

    float ga0 = 0.f, ga1 = 0.f, ga2 = 0.f, ga3 = 0.f;

    // ---- prologue: tile 0 ----
    STAGE_LOAD(0);
    STAGE_WRITE_ALL();
    asm volatile("s_waitcnt lgkmcnt(0)" ::: "memory");
    __builtin_amdgcn_s_barrier();

    #pragma unroll
    for (int tt = 0; tt < NT; ++tt) {
        // qkc for this tile (E-cols only)
        float4 qkv4 = {0.f, 0.f, 0.f, 0.f};
        if (c < 8)
            qkv4 = *(const float4*)(QKc + ((size_t)bn * HH + c) * NN
                                    + tt * TR + wq * 16 + mq * 4);
        // prefetch next tile into regs (stays in flight across the MFMA)
        if (tt + 1 < NT) STAGE_LOAD(tt + 1);

        // ---- MFMA: E/G for this wave's 16 rows x 16 cols ----
        const int mrow = wq * 16 + c;
        f32x4 acc = {0.f, 0.f, 0.f, 0.f};
        #pragma unroll
        for (int kb = 0; kb < 4; ++kb) {
            const int ck = kb * 4 + mq;
            uint4 av = ebuf4[mrow * 16 + (ck ^ (mrow & 15))];
            acc = __builtin_amdgcn_mfma_f32_16x16x32_bf16(
                      *(short8*)&av, wB[kb], acc, 0, 0, 0);
        }

        // ---- epilogue: _E into persistent ET / G accumulate ----
        const int mloc = tt * TR + wq * 16 + mq * 4;
        if (c < 8) {
            ET[c * NN + mloc + 0] = acc[0] + qkv4.x;
            ET[c * NN + mloc + 1] = acc[1] + qkv4.y;
            ET[c * NN + mloc + 2] = acc[2] + qkv4.z;
            ET[c * NN + mloc + 3] = acc[3] + qkv4.w;
        } else {
            ga0 += 1.f / (1.f + __expf(-acc[0]));
            ga1 += 1.f / (1.f + __expf(-acc[1]));
            ga2 += 1.f / (1.f + __expf(-acc[2]));
            ga3 += 1.f / (1.f + __expf(-acc[3]));
        }
        asm volatile("s_waitcnt lgkmcnt(0)" ::: "memory");
        __builtin_amdgcn_s_barrier();   // ebuf reads done; ET writes visible

        // ---- refill ebuf from prefetched regs ----
        if (tt + 1 < NT) {
            STAGE_WRITE_ALL();          // compiler waits the prefetch vmcnt
            asm volatile("s_waitcnt lgkmcnt(0)" ::: "memory");
            __builtin_amdgcn_s_barrier();
        }
    }

    // ---- G reduction -> dyn_cent ----
    if (c >= 8) {
        float s = ga0 + ga1 + ga2 + ga3;
        s += __shfl_xor(s, 16, 64);
        s += __shfl_xor(s, 32, 64);
        if (lane < 16) Gred[wq * 8 + (c - 8)] = s;
    }
    __syncthreads();
    if (t < 8) {
        float s = 0.f;
        #pragma unroll
        for (int w = 0; w < 8; ++w) s += Gred[w * 8 + t];
        dc[t] = log1pf(s);
    }
    __syncthreads();

    // ---- e_out phase: all 512 rows from persistent ET ----
    {
        float4 oe[8];
        #pragma unroll
        for (int h = 0; h < 8; ++h)
            oe[h] = ((const float4*)O_e)[h * 32 + c4o];
        float4* __restrict__ out4 = (float4*)e_out + (size_t)bn * NN * 32;
        #pragma unroll 4
        for (int it = 0; it < 32; ++it) {
            const int m = mr0 + it * 16;
            float4 rr{0.f, 0.f, 0.f, 0.f};
            #pragma unroll
            for (int h = 0; h < 8; ++h) {
                const float ev = ET[h * NN + m];   // broadcast read
                rr.x += ev * oe[h].x;
                rr.y += ev * oe[h].y;
                rr.z += ev * oe[h].z;
                rr.w += ev * oe[h].w;
            }
            out4[m * 32 + c4o] = rr;
        }
    }

    // ---- softmax + AV: wave wq owns head wq ----
    {
        const int h = wq;
        float vals[8];
        float rmax = -1e30f;
        #pragma unroll
        for (int k = 0; k < 8; ++k) {
            vals[k] = ET[h * NN + k * 64 + lane];
            rmax = fmaxf(rmax, vals[k]);
        }
        #pragma unroll
        for (int off = 32; off >= 1; off >>= 1)
            rmax = fmaxf(rmax, __shfl_xor(rmax, off, 64));
        float sum = 0.f;
        #pragma unroll
        for (int k = 0; k < 8; ++k) sum += __expf(vals[k] - rmax);
        #pragma unroll
        for (int off = 32; off >= 1; off >>= 1)
            sum += __shfl_xor(sum, off, 64);
        const float factor = dc[h] / sum;

        const int ddx = lane & 15, mg = lane >> 4;
        const float* __restrict__ vb = Vw + ((size_t)(b * HH + h) * NN) * DKK;
        float av = 0.f;
        #pragma unroll 4
        for (int m = mg; m < NN; m += 4) {
            const float p = __expf(ET[h * NN + m] - rmax);
            av += p * vb[m * DKK + ddx];
        }
        av += __shfl_xor(av, 16, 64);
        av += __shfl_xor(av, 32, 64);
        if (mg == 0) vout[h * DKK + ddx] = av * factor;
    }
    __syncthreads();

    // ---- n_out = vout @ O_n ----
    if (t < DD) {
        float a3 = 0.f;
        #pragma unroll 4
        for (int d = 0; d < DD; ++d) a3 += vout[d] * O_n[d * DD + t];
        n_out[(size_t)bn * DD + t] = a3;
    }
    #undef STAGE_LOAD
    #undef STAGE_WRITE
    #undef STAGE_WRITE_ALL
}

extern "C" void kernel_launch(void* const* d_in, const int* in_sizes, int n_in,
                              void* d_out, int out_size, void* d_ws, size_t ws_size,
                              hipStream_t stream)
{
    const float* n_ptr = (const float*)d_in[0];
    const float* e     = (const float*)d_in[1];
    const float* W_qkv = (const float*)d_in[2];
    const float* O_n   = (const float*)d_in[3];
    const float* W_g   = (const float*)d_in[4];
    const float* W_e   = (const float*)d_in[5];
    const float* O_e   = (const float*)d_in[6];

    float* n_out = (float*)d_out;
    float* e_out = n_out + (size_t)BB * NN * DD;

    float* Qw   = (float*)d_ws;                          // 3 x 0.5MB
    float* Kw   = Qw + (size_t)BB * HH * NN * DKK;
    float* Vw   = Kw + (size_t)BB * HH * NN * DKK;
    float* QKc  = Vw + (size_t)BB * HH * NN * DKK;       // 16.8MB
    float* WegT = QKc + (size_t)BB * HH * NN * NN;       // 8KB

    qkv_kernel<<<BB * NN + 16, 128, 0, stream>>>(n_ptr, W_qkv, W_g, W_e,
                                                 Qw, Kw, Vw, WegT);
    qk_kernel<<<BB * HH * 16, 256, 0, stream>>>(Qw, Kw, QKc);
    eg_kernel<<<BB * NN, 512, 0, stream>>>(e, WegT, O_e, QKc, Vw, O_n,
                                           n_out, e_out);
}

// Round 11
// 155.953 us; speedup vs baseline: 1.7809x; 1.1091x over previous
//
#include <hip/hip_runtime.h>
#include <math.h>

#define BB 2
#define NN 512
#define DD 128
#define HH 8
#define DKK 16
#define TR 128           // tile rows
#define NT (NN / TR)     // 4 tiles per (b,n)
#define ETS 516          // padded ET row stride (516 % 32 = 4 -> conflict-free RMW)

typedef __attribute__((ext_vector_type(8))) short short8;
typedef __attribute__((ext_vector_type(4))) float f32x4;

__device__ __forceinline__ float dot4(float4 a, float4 b) {
    return a.x*b.x + a.y*b.y + a.z*b.z + a.w*b.w;
}
// RNE f32 -> bf16 pack (a in low, b in high)
__device__ __forceinline__ unsigned pk_bf16(float a, float b) {
    unsigned ua = __float_as_uint(a), ub = __float_as_uint(b);
    ua = (ua + 0x7FFFu + ((ua >> 16) & 1u)) >> 16;
    ub = (ub + 0x7FFFu + ((ub >> 16) & 1u)) >> 16;
    return ua | (ub << 16);
}

// ---------------- Kernel 1: QKV projection + W_egT staging ----------------
__global__ __launch_bounds__(128)
void qkv_kernel(const float* __restrict__ n_in,
                const float* __restrict__ W_qkv,
                const float* __restrict__ W_g,
                const float* __restrict__ W_e,
                float* __restrict__ Qw, float* __restrict__ Kw,
                float* __restrict__ Vw, float* __restrict__ WegT)
{
    const int bid = blockIdx.x;
    if (bid >= BB * NN) {                    // 16 trailing blocks: WegT[col][d]
        const int col = bid - BB * NN;       // 0..15
        const int t = threadIdx.x;           // 0..127
        WegT[col * DD + t] = (col < 8) ? W_e[t * HH + col]
                                       : W_g[t * HH + (col - 8)];
        return;
    }
    __shared__ float nrow[DD];
    const int bn = bid;
    const int b  = bn >> 9;
    const int nr = bn & 511;
    const int t  = threadIdx.x;
    nrow[t] = n_in[(size_t)bn * DD + t];
    __syncthreads();
    const int h = t >> 4, dk = t & 15;
    const size_t dst = ((size_t)(b * HH + h) * NN + nr) * DKK + dk;
    float accq = 0.f, acck = 0.f, accv = 0.f;
    #pragma unroll 8
    for (int d = 0; d < DD; ++d) {
        const float nv = nrow[d];
        const float* wr = W_qkv + (size_t)d * 3 * DD;
        accq += nv * wr[t];
        acck += nv * wr[t + 128];
        accv += nv * wr[t + 256];
    }
    Qw[dst] = accq;
    Kw[dst] = acck;
    Vw[dst] = accv;
}

// ---------------- Kernel 2: fully fused QK + E/G (MFMA) + e_out + softmax/AV + n_out
// One block per (b,n), 512 threads = 8 waves. Clamped QK scores computed in
// the prologue (wave = head, K panel L2-resident) directly into padded ET;
// tile-loop epilogue is a conflict-free LDS float4 RMW. No QKc buffer.
__global__ __attribute__((amdgpu_flat_work_group_size(512, 512),
                          amdgpu_waves_per_eu(2, 4)))
void eg_kernel(const float* __restrict__ e,
               const float* __restrict__ WegT,
               const float* __restrict__ O_e,
               const float* __restrict__ Qw,
               const float* __restrict__ Kw,
               const float* __restrict__ Vw,
               const float* __restrict__ O_n,
               float* __restrict__ n_out,
               float* __restrict__ e_out)
{
    __shared__ __align__(16) uint4 ebuf4[TR * 16];   // 32KB bf16 tile (single)
    __shared__ __align__(16) float ET[HH * ETS];     // 16.5KB persistent _E [h][m]
    __shared__ float Gred[64];
    __shared__ float dc[HH];
    __shared__ __align__(16) float vout[DD];

    const int t    = threadIdx.x;
    const int bn   = blockIdx.x;
    const int b    = bn >> 9;
    const int nr   = bn & 511;
    const int wq   = t >> 6;
    const int lane = t & 63;
    const int c    = lane & 15;      // MFMA C/D col (= W col / head)
    const int mq   = lane >> 4;      // C/D row group; also A/B k-group
    const int c4o  = t & 31;         // e_out float4 column
    const int mr0  = t >> 5;         // e_out row base 0..15

    const float4* __restrict__ e4    = (const float4*)e + (size_t)bn * NN * 32;
    const float4* __restrict__ WegT4 = (const float4*)WegT;

    // ---- B fragments: W[col=c][k] -> bf16, 4 k-steps (16 VGPR) ----
    short8 wB[4];
    #pragma unroll
    for (int kb = 0; kb < 4; ++kb) {
        const float4 wa = WegT4[c * 32 + kb * 8 + mq * 2];
        const float4 wb = WegT4[c * 32 + kb * 8 + mq * 2 + 1];
        uint4 u;
        u.x = pk_bf16(wa.x, wa.y); u.y = pk_bf16(wa.z, wa.w);
        u.z = pk_bf16(wb.x, wb.y); u.w = pk_bf16(wb.z, wb.w);
        wB[kb] = *(short8*)&u;
    }

    // stage-load regs: 8 float4 (32 VGPR)
    float4 pa0, pa1, pa2, pa3, pb0, pb1, pb2, pb3;

    #define STAGE_LOAD(tile)                                                  \
    {                                                                         \
        const float4* __restrict__ sp = e4 + (size_t)(tile) * 4096 + 2 * t;   \
        pa0 = sp[0];    pb0 = sp[1];                                          \
        pa1 = sp[1024]; pb1 = sp[1025];                                       \
        pa2 = sp[2048]; pb2 = sp[2049];                                       \
        pa3 = sp[3072]; pb3 = sp[3073];                                       \
    }
    #define STAGE_WRITE(P, A, B)                                              \
    {                                                                         \
        const int ms = (P) * 32 + (t >> 4), ck = t & 15;                      \
        uint4 u;                                                              \
        u.x = pk_bf16(A.x, A.y); u.y = pk_bf16(A.z, A.w);                     \
        u.z = pk_bf16(B.x, B.y); u.w = pk_bf16(B.z, B.w);                     \
        ebuf4[ms * 16 + (ck ^ (ms & 15))] = u;                                \
    }
    #define STAGE_WRITE_ALL()                                                 \
    {                                                                         \
        STAGE_WRITE(0, pa0, pb0); STAGE_WRITE(1, pa1, pb1);                   \
        STAGE_WRITE(2, pa2, pb2); STAGE_WRITE(3, pa3, pb3);                   \
    }

    float ga0 = 0.f, ga1 = 0.f, ga2 = 0.f, ga3 = 0.f;

    // ---- prologue: issue tile-0 e loads (HBM), then QK scores (L2) ----
    STAGE_LOAD(0);

    {   // wave wq = head h; clamped scores -> ET[h][m]
        const int h = wq;
        const float4* __restrict__ qp =
            (const float4*)(Qw + ((size_t)(b * HH + h) * NN + nr) * DKK);
        const float4 q0 = qp[0], q1 = qp[1], q2 = qp[2], q3 = qp[3];
        const float4* __restrict__ kb =
            (const float4*)(Kw + ((size_t)(b * HH + h) * NN) * DKK);
        #pragma unroll
        for (int k = 0; k < 8; ++k) {
            const int m = k * 64 + lane;
            float s = dot4(q0, kb[m * 4 + 0]) + dot4(q1, kb[m * 4 + 1])
                    + dot4(q2, kb[m * 4 + 2]) + dot4(q3, kb[m * 4 + 3]);
            s *= 0.25f;
            ET[h * ETS + m] = fminf(5.f, fmaxf(-5.f, s));
        }
    }

    STAGE_WRITE_ALL();
    asm volatile("s_waitcnt lgkmcnt(0)" ::: "memory");
    __builtin_amdgcn_s_barrier();

    #pragma unroll
    for (int tt = 0; tt < NT; ++tt) {
        // prefetch next tile into regs (stays in flight across the MFMA)
        if (tt + 1 < NT) STAGE_LOAD(tt + 1);

        // ---- MFMA: E/G for this wave's 16 rows x 16 cols ----
        const int mrow = wq * 16 + c;
        f32x4 acc = {0.f, 0.f, 0.f, 0.f};
        #pragma unroll
        for (int kb = 0; kb < 4; ++kb) {
            const int ck = kb * 4 + mq;
            uint4 av = ebuf4[mrow * 16 + (ck ^ (mrow & 15))];
            acc = __builtin_amdgcn_mfma_f32_16x16x32_bf16(
                      *(short8*)&av, wB[kb], acc, 0, 0, 0);
        }

        // ---- epilogue: _E = acc + clamped_score (LDS RMW) / G accumulate ----
        const int mloc = tt * TR + wq * 16 + mq * 4;
        if (c < 8) {
            float4 prev = *(float4*)&ET[c * ETS + mloc];
            prev.x += acc[0]; prev.y += acc[1];
            prev.z += acc[2]; prev.w += acc[3];
            *(float4*)&ET[c * ETS + mloc] = prev;
        } else {
            ga0 += 1.f / (1.f + __expf(-acc[0]));
            ga1 += 1.f / (1.f + __expf(-acc[1]));
            ga2 += 1.f / (1.f + __expf(-acc[2]));
            ga3 += 1.f / (1.f + __expf(-acc[3]));
        }
        asm volatile("s_waitcnt lgkmcnt(0)" ::: "memory");
        __builtin_amdgcn_s_barrier();   // ebuf reads done; ET writes visible

        // ---- refill ebuf from prefetched regs ----
        if (tt + 1 < NT) {
            STAGE_WRITE_ALL();          // compiler waits the prefetch vmcnt
            asm volatile("s_waitcnt lgkmcnt(0)" ::: "memory");
            __builtin_amdgcn_s_barrier();
        }
    }

    // ---- G reduction -> dyn_cent ----
    if (c >= 8) {
        float s = ga0 + ga1 + ga2 + ga3;
        s += __shfl_xor(s, 16, 64);
        s += __shfl_xor(s, 32, 64);
        if (lane < 16) Gred[wq * 8 + (c - 8)] = s;
    }
    __syncthreads();
    if (t < 8) {
        float s = 0.f;
        #pragma unroll
        for (int w = 0; w < 8; ++w) s += Gred[w * 8 + t];
        dc[t] = log1pf(s);
    }
    __syncthreads();

    // ---- e_out phase: all 512 rows from persistent ET ----
    {
        float4 oe[8];
        #pragma unroll
        for (int h = 0; h < 8; ++h)
            oe[h] = ((const float4*)O_e)[h * 32 + c4o];
        float4* __restrict__ out4 = (float4*)e_out + (size_t)bn * NN * 32;
        #pragma unroll 4
        for (int it = 0; it < 32; ++it) {
            const int m = mr0 + it * 16;
            float4 rr{0.f, 0.f, 0.f, 0.f};
            #pragma unroll
            for (int h = 0; h < 8; ++h) {
                const float ev = ET[h * ETS + m];   // broadcast read
                rr.x += ev * oe[h].x;
                rr.y += ev * oe[h].y;
                rr.z += ev * oe[h].z;
                rr.w += ev * oe[h].w;
            }
            out4[m * 32 + c4o] = rr;
        }
    }

    // ---- softmax + AV: wave wq owns head wq ----
    {
        const int h = wq;
        float vals[8];
        float rmax = -1e30f;
        #pragma unroll
        for (int k = 0; k < 8; ++k) {
            vals[k] = ET[h * ETS + k * 64 + lane];
            rmax = fmaxf(rmax, vals[k]);
        }
        #pragma unroll
        for (int off = 32; off >= 1; off >>= 1)
            rmax = fmaxf(rmax, __shfl_xor(rmax, off, 64));
        float sum = 0.f;
        #pragma unroll
        for (int k = 0; k < 8; ++k) sum += __expf(vals[k] - rmax);
        #pragma unroll
        for (int off = 32; off >= 1; off >>= 1)
            sum += __shfl_xor(sum, off, 64);
        const float factor = dc[h] / sum;

        const int ddx = lane & 15, mg = lane >> 4;
        const float* __restrict__ vb = Vw + ((size_t)(b * HH + h) * NN) * DKK;
        float av = 0.f;
        #pragma unroll 4
        for (int m = mg; m < NN; m += 4) {
            const float p = __expf(ET[h * ETS + m] - rmax);
            av += p * vb[m * DKK + ddx];
        }
        av += __shfl_xor(av, 16, 64);
        av += __shfl_xor(av, 32, 64);
        if (mg == 0) vout[h * DKK + ddx] = av * factor;
    }
    __syncthreads();

    // ---- n_out = vout @ O_n ----
    if (t < DD) {
        float a3 = 0.f;
        #pragma unroll 4
        for (int d = 0; d < DD; ++d) a3 += vout[d] * O_n[d * DD + t];
        n_out[(size_t)bn * DD + t] = a3;
    }
    #undef STAGE_LOAD
    #undef STAGE_WRITE
    #undef STAGE_WRITE_ALL
}

extern "C" void kernel_launch(void* const* d_in, const int* in_sizes, int n_in,
                              void* d_out, int out_size, void* d_ws, size_t ws_size,
                              hipStream_t stream)
{
    const float* n_ptr = (const float*)d_in[0];
    const float* e     = (const float*)d_in[1];
    const float* W_qkv = (const float*)d_in[2];
    const float* O_n   = (const float*)d_in[3];
    const float* W_g   = (const float*)d_in[4];
    const float* W_e   = (const float*)d_in[5];
    const float* O_e   = (const float*)d_in[6];

    float* n_out = (float*)d_out;
    float* e_out = n_out + (size_t)BB * NN * DD;

    float* Qw   = (float*)d_ws;                          // 3 x 0.5MB
    float* Kw   = Qw + (size_t)BB * HH * NN * DKK;
    float* Vw   = Kw + (size_t)BB * HH * NN * DKK;
    float* WegT = Vw + (size_t)BB * HH * NN * DKK;       // 8KB

    qkv_kernel<<<BB * NN + 16, 128, 0, stream>>>(n_ptr, W_qkv, W_g, W_e,
                                                 Qw, Kw, Vw, WegT);
    eg_kernel<<<BB * NN, 512, 0, stream>>>(e, WegT, O_e, Qw, Kw, Vw, O_n,
                                           n_out, e_out);
}